// Round 15
// baseline (96.853 us; speedup 1.0000x reference)
//
#include <hip/hip_runtime.h>

// alpha-entmax: R10 solver (log-log IQI/secant + it0 linear power-law seed,
// DPP reductions, count-first dense path, nontemporal streaming) slimmed to
// fit 64 VGPR honestly -> 8 blocks/CU, 32 waves/CU (was ~16):
//  - p[] dropped: recomputed at the converged w in the epilogue, fused with
//    the store (bitwise-identical values; frees 16 VGPRs)
//  - vals[] aliased into xs[] (frees 16 VGPRs)
//  - cidx dropped (LDS 24->16 KB): ballot-replay gather via 16-bit actmask
//  - -m folded into the eval: u = xs[k] + (w - m); no shift pass
// __launch_bounds__(256, 8): 8 blocks/CU; VGPR cap 64 fits (~45-50 live).

typedef float f4 __attribute__((ext_vector_type(4)));

template <int CTRL, int RM>
__device__ __forceinline__ float dpp_add(float x) {
  int s = __builtin_amdgcn_update_dpp(0, __builtin_bit_cast(int, x),
                                      CTRL, RM, 0xF, false);
  return x + __builtin_bit_cast(float, s);
}
template <int CTRL, int RM>
__device__ __forceinline__ float dpp_max(float x) {
  int s = __builtin_amdgcn_update_dpp((int)0xFF800000,
                                      __builtin_bit_cast(int, x),
                                      CTRL, RM, 0xF, false);
  return fmaxf(x, __builtin_bit_cast(float, s));
}
__device__ __forceinline__ float wave_sum(float x) {
  x = dpp_add<0xB1, 0xF>(x);    // quad_perm xor1
  x = dpp_add<0x4E, 0xF>(x);    // quad_perm xor2
  x = dpp_add<0x141, 0xF>(x);   // row_half_mirror (xor4)
  x = dpp_add<0x140, 0xF>(x);   // row_mirror (xor8)
  x = dpp_add<0x142, 0xA>(x);   // row_bcast15 -> rows 1,3
  x = dpp_add<0x143, 0xC>(x);   // row_bcast31 -> rows 2,3
  return __builtin_bit_cast(float,
      __builtin_amdgcn_readlane(__builtin_bit_cast(int, x), 63));
}
__device__ __forceinline__ float wave_max(float x) {
  x = dpp_max<0xB1, 0xF>(x);
  x = dpp_max<0x4E, 0xF>(x);
  x = dpp_max<0x141, 0xF>(x);
  x = dpp_max<0x140, 0xF>(x);
  x = dpp_max<0x142, 0xA>(x);
  x = dpp_max<0x143, 0xC>(x);
  return __builtin_bit_cast(float,
      __builtin_amdgcn_readlane(__builtin_bit_cast(int, x), 63));
}

#define MAXIT 12

__global__ __launch_bounds__(256, 8) void entmax_slim(
    const float* __restrict__ X, const float* __restrict__ A,
    float* __restrict__ O, int nrows) {
  __shared__ float cval[4][1024];            // 16 KB: compacted xs / p staging

  const int lane = threadIdx.x & 63;
  const int wid  = threadIdx.x >> 6;
  const long long row = (long long)blockIdx.x * 4 + wid;
  if (row >= nrows) return;

  const f4* xr4 = reinterpret_cast<const f4*>(X + row * 1024);
  f4* or4       = reinterpret_cast<f4*>(O + row * 1024);

  const int h = (int)((row >> 10) & 15);     // [B,H,Q] flattened, Q=1024
  const float a   = 1.01f + 0.98f * A[h];
  const float am1 = a - 1.0f;                // = 1/p
  const float inv = 1.0f / am1;              // = p in (1.01, 100]

  float xs[16];                              // x*am1 (UNshifted)
#pragma unroll
  for (int c = 0; c < 4; ++c) {
    f4 t = __builtin_nontemporal_load(xr4 + c * 64 + lane);
    xs[4*c+0] = t[0] * am1; xs[4*c+1] = t[1] * am1;
    xs[4*c+2] = t[2] * am1; xs[4*c+3] = t[3] * am1;
  }
  float m = xs[0];
#pragma unroll
  for (int j = 1; j < 16; ++j) m = fmaxf(m, xs[j]);
  m = wave_max(m);
  const float thr = m - 1.0f;                // active iff xs > thr (fixed set)

  // ---- activity mask + count (nact wave-uniform) ----
  int actmask = 0, nact = 0;
#pragma unroll
  for (int j = 0; j < 16; ++j) {
    const bool act = xs[j] > thr;
    if (act) actmask |= (1 << j);
    nact += (int)__popcll(__ballot(act));
  }
  const int  K      = (nact + 63) >> 6;
  const bool direct = (K == 16);             // dense: xs used as-is

  if (!direct) {                             // compact xs into LDS, read back
    int base = 0;
#pragma unroll
    for (int j = 0; j < 16; ++j) {
      const bool act = (actmask >> j) & 1;
      const unsigned long long mk = __ballot(act);
      if (act)
        cval[wid][base + __popcll(mk & ((1ull << lane) - 1ull))] = xs[j];
      base += __popcll(mk);
    }
    for (int pos = nact + lane; pos < (K << 6); pos += 64)
      cval[wid][pos] = -3.0e38f;             // pad: u == 0 forever
    asm volatile("s_waitcnt lgkmcnt(0)" ::: "memory");
#pragma unroll
    for (int k = 0; k < 16; ++k)
      if (k < K) xs[k] = cval[wid][lane + (k << 6)];
  }

  // ---- it0 at w=1 (vw = 1-m): f and g -> linear log-log seed ----
  float lwlo = -10.0f * am1;                 // log2(d^(-1/p)) lower bracket
  float lwhi = 0.0f;
  float w = 1.0f, lw = 0.0f;
  float f, lw_p, lf_p;
  float lw_pp = 0.0f, lf_pp = 0.0f;
  bool have2 = false;
  {
    const float c1  = inv - 1.0f;
    const float vw0 = 1.0f - m;
    float fs = 0.0f, gs = 0.0f;
#pragma unroll
    for (int k = 0; k < 16; ++k)
      if (k < K) {
        float u  = fmaxf(xs[k] + vw0, 0.0f);
        float e  = __builtin_amdgcn_exp2f(c1 * __builtin_amdgcn_logf(u));
        fs = fmaf(e, u, fs); gs += e;        // u^p, u^(p-1)
      }
    f = wave_sum(fs);
    const float g = wave_sum(gs);            // g >= 1, f >= 1 at w=1
    lw_p = 0.0f; lf_p = __builtin_amdgcn_logf(f);
    if (fabsf(f - 1.0f) > 1e-6f) {
      // q0 = p*g/f at w=1; lw1 = -lf0/q0
      float lwn = -lf_p * f * am1 / g;
      if (!(lwn > lwlo) || !(lwn < lwhi)) lwn = 0.5f * (lwlo + lwhi);
      w = __builtin_amdgcn_exp2f(lwn); lw = lwn;

      // ---- IQI / secant iterations (f only) ----
      for (int it = 1; it < MAXIT; ++it) {
        const float vw = w - m;
        float fs2 = 0.0f;
#pragma unroll
        for (int k = 0; k < 16; ++k)
          if (k < K) {
            float u = fmaxf(xs[k] + vw, 0.0f);
            fs2 += __builtin_amdgcn_exp2f(inv * __builtin_amdgcn_logf(u));
          }
        f = wave_sum(fs2);

        float lwnew;
        if (f > 0.0f) {
          if (fabsf(f - 1.0f) <= 1e-6f) break;
          const float lf = __builtin_amdgcn_logf(f);
          if (f > 1.0f) lwhi = lw; else lwlo = lw;

          float cand = 0.0f; bool got = false;
          if (have2) {
            // inverse quadratic interpolation to lf = 0
            const float d01 = lf - lf_p, d02 = lf - lf_pp, d12 = lf_p - lf_pp;
            const float r01 = __builtin_amdgcn_rcpf(d01);
            const float r02 = __builtin_amdgcn_rcpf(d02);
            const float r12 = __builtin_amdgcn_rcpf(d12);
            cand = lw    * lf_p * lf_pp * r01 * r02
                 - lw_p  * lf   * lf_pp * r01 * r12
                 + lw_pp * lf   * lf_p  * r02 * r12;
            got = (cand > lwlo) && (cand < lwhi);   // inf/nan fail here
          }
          if (!got) {
            const float si = (lw - lw_p) / (lf - lf_p); // secant
            cand = lw - lf * si;
            if (!(si > 0.0f) || !(cand > lwlo) || !(cand < lwhi))
              cand = 0.5f * (lwlo + lwhi);            // geometric bisect
          }
          lw_pp = lw_p; lf_pp = lf_p; lw_p = lw; lf_p = lf; have2 = true;
          lwnew = cand;
        } else {                              // underflow: w below root
          lwlo = lw;
          lwnew = 0.5f * (lwlo + lwhi);
        }
        const float wnew = __builtin_amdgcn_exp2f(lwnew);
        // |dP| <= p*dtau; tol 2e-5 rel adds <= ~6e-3 worst-case (thr 2e-2)
        if (!(fabsf(wnew - w) > 2e-5f * fmaxf(fabsf(m - w), 1.0f))) break;
        w = wnew; lw = lwnew;
      }
    }
  }

  // ---- epilogue: recompute p at the converged w (== last-eval values),
  //      normalize by f, store ----
  const float r  = 1.0f / f;
  const float vw = w - m;
  if (direct) {                               // fused recompute + store
#pragma unroll
    for (int c = 0; c < 4; ++c) {
      f4 t;
#pragma unroll
      for (int k = 0; k < 4; ++k) {
        float u = fmaxf(xs[4*c+k] + vw, 0.0f);
        t[k] = __builtin_amdgcn_exp2f(inv * __builtin_amdgcn_logf(u)) * r;
      }
      __builtin_nontemporal_store(t, or4 + c * 64 + lane);
    }
  } else {
    // recompute compacted p, write linear, ballot-replay gather, store
#pragma unroll
    for (int k = 0; k < 16; ++k)
      if (k < K) {
        float u = fmaxf(xs[k] + vw, 0.0f);
        cval[wid][lane + (k << 6)] =
            __builtin_amdgcn_exp2f(inv * __builtin_amdgcn_logf(u)) * r;
      }
    asm volatile("s_waitcnt lgkmcnt(0)" ::: "memory");
    int base = 0;
#pragma unroll
    for (int c = 0; c < 4; ++c) {
      float tmp[4];
#pragma unroll
      for (int k = 0; k < 4; ++k) {
        const int j = 4*c + k;
        const bool act = (actmask >> j) & 1;  // same predicate, same order
        const unsigned long long mk = __ballot(act);
        float v = 0.0f;
        if (act) v = cval[wid][base + __popcll(mk & ((1ull << lane) - 1ull))];
        base += __popcll(mk);
        tmp[k] = v;
      }
      f4 t;
      t[0] = tmp[0]; t[1] = tmp[1]; t[2] = tmp[2]; t[3] = tmp[3];
      __builtin_nontemporal_store(t, or4 + c * 64 + lane);
    }
  }
}

extern "C" void kernel_launch(void* const* d_in, const int* in_sizes, int n_in,
                              void* d_out, int out_size, void* d_ws, size_t ws_size,
                              hipStream_t stream) {
  const float* X = (const float*)d_in[0];
  const float* A = (const float*)d_in[1];
  float* O       = (float*)d_out;
  const int nrows = in_sizes[0] / 1024;                 // 65536
  const int blocks = (nrows + 3) / 4;                   // 4 rows (waves) per block
  hipLaunchKernelGGL(entmax_slim, dim3(blocks), dim3(256), 0, stream,
                     X, A, O, nrows);
}

// Round 16
// 92.294 us; speedup vs baseline: 1.0494x; 1.0494x over previous
//
#include <hip/hip_runtime.h>

// alpha-entmax: R10 base (log-log IQI/secant + it0 power-law seed + DPP
// reductions + count-first dense path + nontemporal streaming; 93.9 us),
// ONE change: f-convergence break 1e-6 -> 3e-3.
//   Output is p_j(tau)/f(tau) — normalized by the ACTUAL sum — so stopping
//   at f = 1+eps only misplaces tau by dtau = eps/(p*g); output error
//   <= eps*(1+g)/g <= 2*eps (g >= 1 at the root). eps = 3e-3 adds <= 6e-3
//   vs the 2e-2 threshold, and lets the well-seeded eval1 exit immediately
//   (2 evals instead of 3 on most rows).

typedef float f4 __attribute__((ext_vector_type(4)));

template <int CTRL, int RM>
__device__ __forceinline__ float dpp_add(float x) {
  int s = __builtin_amdgcn_update_dpp(0, __builtin_bit_cast(int, x),
                                      CTRL, RM, 0xF, false);
  return x + __builtin_bit_cast(float, s);
}
template <int CTRL, int RM>
__device__ __forceinline__ float dpp_max(float x) {
  int s = __builtin_amdgcn_update_dpp((int)0xFF800000,
                                      __builtin_bit_cast(int, x),
                                      CTRL, RM, 0xF, false);
  return fmaxf(x, __builtin_bit_cast(float, s));
}
__device__ __forceinline__ float wave_sum(float x) {
  x = dpp_add<0xB1, 0xF>(x);    // quad_perm xor1
  x = dpp_add<0x4E, 0xF>(x);    // quad_perm xor2
  x = dpp_add<0x141, 0xF>(x);   // row_half_mirror (xor4)
  x = dpp_add<0x140, 0xF>(x);   // row_mirror (xor8)
  x = dpp_add<0x142, 0xA>(x);   // row_bcast15 -> rows 1,3
  x = dpp_add<0x143, 0xC>(x);   // row_bcast31 -> rows 2,3
  return __builtin_bit_cast(float,
      __builtin_amdgcn_readlane(__builtin_bit_cast(int, x), 63));
}
__device__ __forceinline__ float wave_max(float x) {
  x = dpp_max<0xB1, 0xF>(x);
  x = dpp_max<0x4E, 0xF>(x);
  x = dpp_max<0x141, 0xF>(x);
  x = dpp_max<0x140, 0xF>(x);
  x = dpp_max<0x142, 0xA>(x);
  x = dpp_max<0x143, 0xC>(x);
  return __builtin_bit_cast(float,
      __builtin_amdgcn_readlane(__builtin_bit_cast(int, x), 63));
}

#define MAXIT 12
#define FEPS 3e-3f

__global__ __launch_bounds__(256) void entmax_iqi2(
    const float* __restrict__ X, const float* __restrict__ A,
    float* __restrict__ O, int nrows) {
  __shared__ float          cval[4][1024];
  __shared__ unsigned short cidx[4][1024];

  const int lane = threadIdx.x & 63;
  const int wid  = threadIdx.x >> 6;
  const long long row = (long long)blockIdx.x * 4 + wid;
  if (row >= nrows) return;

  const f4* xr4 = reinterpret_cast<const f4*>(X + row * 1024);
  f4* or4       = reinterpret_cast<f4*>(O + row * 1024);

  const int h = (int)((row >> 10) & 15);     // [B,H,Q] flattened, Q=1024
  const float a   = 1.01f + 0.98f * A[h];
  const float am1 = a - 1.0f;                // = 1/p
  const float inv = 1.0f / am1;              // = p in (1.01, 100]
  const float c1  = inv - 1.0f;

  float xs[16];
#pragma unroll
  for (int c = 0; c < 4; ++c) {
    f4 t = __builtin_nontemporal_load(xr4 + c * 64 + lane);
    xs[4*c+0] = t[0] * am1; xs[4*c+1] = t[1] * am1;
    xs[4*c+2] = t[2] * am1; xs[4*c+3] = t[3] * am1;
  }
  float m = xs[0];
#pragma unroll
  for (int j = 1; j < 16; ++j) m = fmaxf(m, xs[j]);
  m = wave_max(m);
#pragma unroll
  for (int j = 0; j < 16; ++j) xs[j] -= m;   // zs <= 0; active iff zs > -1

  // ---- count-first (nact wave-uniform) ----
  int nact = 0;
#pragma unroll
  for (int j = 0; j < 16; ++j)
    nact += (int)__popcll(__ballot(xs[j] > -1.0f));
  const int  K      = (nact + 63) >> 6;
  const bool direct = (K == 16);             // dense: solve in original order

  float vals[16];
  if (direct) {
#pragma unroll
    for (int k = 0; k < 16; ++k) vals[k] = xs[k];
  } else {
    int base = 0;
#pragma unroll
    for (int c = 0; c < 4; ++c) {
#pragma unroll
      for (int k = 0; k < 4; ++k) {
        const int j = 4*c + k;
        const bool act = xs[j] > -1.0f;
        const unsigned long long mk = __ballot(act);
        if (act) {
          const int pos = base + __popcll(mk & ((1ull << lane) - 1ull));
          cval[wid][pos] = xs[j];
          cidx[wid][pos] = (unsigned short)(c * 256 + lane * 4 + k);
        }
        base += __popcll(mk);
      }
    }
    for (int pos = nact + lane; pos < (K << 6); pos += 64)
      cval[wid][pos] = -2.0f;                // pad: never active
    asm volatile("s_waitcnt lgkmcnt(0)" ::: "memory");
#pragma unroll
    for (int k = 0; k < 16; ++k)
      if (k < K) vals[k] = cval[wid][lane + (k << 6)];
  }

  // ---- it0: eval at w=1 with g; exact local power-law seed ----
  float lwlo = -10.0f * am1;                 // log2(d^(-1/p)) lower bracket
  float lwhi = 0.0f;
  float w = 1.0f, lw = 0.0f;
  float p[16];
  float f, lw_p, lf_p;
  float lw_pp = 0.0f, lf_pp = 0.0f;
  bool have2 = false;
  {
    float fs = 0.0f, gs = 0.0f;
#pragma unroll
    for (int k = 0; k < 16; ++k)
      if (k < K) {
        float u  = fmaxf(vals[k] + 1.0f, 0.0f);
        float e  = __builtin_amdgcn_exp2f(c1 * __builtin_amdgcn_logf(u));
        float pe = e * u;
        p[k] = pe; fs += pe; gs += e;
      }
    f = wave_sum(fs);
    const float g = wave_sum(gs);            // g >= 1, f >= 1 at w=1
    lw_p = 0.0f; lf_p = __builtin_amdgcn_logf(f);
    if (fabsf(f - 1.0f) > FEPS) {
      // q0 = p*g*w/f (w=1); lw1 = -lf0/q0
      float lwn = -lf_p * f * am1 / g;
      if (!(lwn > lwlo) || !(lwn < lwhi)) lwn = 0.5f * (lwlo + lwhi);
      w = __builtin_amdgcn_exp2f(lwn); lw = lwn;

      // ---- IQI / secant iterations (f only) ----
      for (int it = 1; it < MAXIT; ++it) {
        float fs2 = 0.0f;
#pragma unroll
        for (int k = 0; k < 16; ++k)
          if (k < K) {
            float u  = fmaxf(vals[k] + w, 0.0f);
            float pe = __builtin_amdgcn_exp2f(
                inv * __builtin_amdgcn_logf(u));
            p[k] = pe; fs2 += pe;
          }
        f = wave_sum(fs2);

        float lwnew;
        if (f > 0.0f) {
          if (fabsf(f - 1.0f) <= FEPS) break;   // normalization absorbs eps
          const float lf = __builtin_amdgcn_logf(f);
          if (f > 1.0f) lwhi = lw; else lwlo = lw;

          float cand = 0.0f; bool got = false;
          if (have2) {
            // inverse quadratic interpolation to lf = 0
            const float d01 = lf - lf_p, d02 = lf - lf_pp, d12 = lf_p - lf_pp;
            const float r01 = __builtin_amdgcn_rcpf(d01);
            const float r02 = __builtin_amdgcn_rcpf(d02);
            const float r12 = __builtin_amdgcn_rcpf(d12);
            cand = lw    * lf_p * lf_pp * r01 * r02
                 - lw_p  * lf   * lf_pp * r01 * r12
                 + lw_pp * lf   * lf_p  * r02 * r12;
            got = (cand > lwlo) && (cand < lwhi);   // inf/nan fail here
          }
          if (!got) {
            const float si = (lw - lw_p) / (lf - lf_p); // secant
            cand = lw - lf * si;
            if (!(si > 0.0f) || !(cand > lwlo) || !(cand < lwhi))
              cand = 0.5f * (lwlo + lwhi);            // geometric bisect
          }
          lw_pp = lw_p; lf_pp = lf_p; lw_p = lw; lf_p = lf; have2 = true;
          lwnew = cand;
        } else {                              // underflow: w below root
          lwlo = lw;
          lwnew = 0.5f * (lwlo + lwhi);
        }
        const float wnew  = __builtin_amdgcn_exp2f(lwnew);
        // |dP| <= p*dtau; tol 2e-5 rel adds <= ~6e-3 worst-case (thr 2e-2)
        if (!(fabsf(wnew - w) > 2e-5f * fmaxf(fabsf(m - w), 1.0f))) break;
        w = wnew; lw = lwnew;
      }
    }
  }

  // ---- epilogue: sum(p[]) == f from the last eval ----
  const float r = 1.0f / f;
  if (direct) {                               // identity layout
#pragma unroll
    for (int c = 0; c < 4; ++c) {
      f4 t;
      t[0] = p[4*c+0] * r; t[1] = p[4*c+1] * r;
      t[2] = p[4*c+2] * r; t[3] = p[4*c+3] * r;
      __builtin_nontemporal_store(t, or4 + c * 64 + lane);
    }
  } else {                                    // zero, scatter by cidx, store
    const f4 z = {0.0f, 0.0f, 0.0f, 0.0f};
#pragma unroll
    for (int c = 0; c < 4; ++c)
      reinterpret_cast<f4*>(&cval[wid][0])[c * 64 + lane] = z;
    asm volatile("s_waitcnt lgkmcnt(0)" ::: "memory");
#pragma unroll
    for (int k = 0; k < 16; ++k)
      if (k < K) {
        const int pos = lane + (k << 6);
        if (pos < nact) cval[wid][cidx[wid][pos]] = p[k] * r;
      }
    asm volatile("s_waitcnt lgkmcnt(0)" ::: "memory");
#pragma unroll
    for (int c = 0; c < 4; ++c) {
      f4 t = reinterpret_cast<const f4*>(&cval[wid][0])[c * 64 + lane];
      __builtin_nontemporal_store(t, or4 + c * 64 + lane);
    }
  }
}

extern "C" void kernel_launch(void* const* d_in, const int* in_sizes, int n_in,
                              void* d_out, int out_size, void* d_ws, size_t ws_size,
                              hipStream_t stream) {
  const float* X = (const float*)d_in[0];
  const float* A = (const float*)d_in[1];
  float* O       = (float*)d_out;
  const int nrows = in_sizes[0] / 1024;                 // 65536
  const int blocks = (nrows + 3) / 4;                   // 4 rows (waves) per block
  hipLaunchKernelGGL(entmax_iqi2, dim3(blocks), dim3(256), 0, stream,
                     X, A, O, nrows);
}

// Round 17
// 91.042 us; speedup vs baseline: 1.0638x; 1.0137x over previous
//
#include <hip/hip_runtime.h>

// alpha-entmax: R15 base (log-log IQI/secant + it0 power-law seed + DPP
// reductions + count-first dense path + nontemporal streaming; 92.3 us),
// TWO bound-justified constant changes:
//  1. FEPS 3e-3 -> 8e-3: output err <= 2*eps (normalization absorbs f-offset)
//     = 1.6e-2 worst case < 2e-2; actual ~2*eps*p_max << that. Converts most
//     remaining 3-eval rows to 2 evals.
//  2. direct threshold K==16 -> K>=12: compaction (~250 cyc fixed) only pays
//     when it removes >4 elems/lane ((16-K)*26*2.2 cyc saved); K=12..15 rows
//     now solve in original order (inactive elems contribute exactly 0:
//     u = zs+w <= w-1 <= 0 -> exp2(-inf) = 0). Eval bound KE = direct?16:K.

typedef float f4 __attribute__((ext_vector_type(4)));

template <int CTRL, int RM>
__device__ __forceinline__ float dpp_add(float x) {
  int s = __builtin_amdgcn_update_dpp(0, __builtin_bit_cast(int, x),
                                      CTRL, RM, 0xF, false);
  return x + __builtin_bit_cast(float, s);
}
template <int CTRL, int RM>
__device__ __forceinline__ float dpp_max(float x) {
  int s = __builtin_amdgcn_update_dpp((int)0xFF800000,
                                      __builtin_bit_cast(int, x),
                                      CTRL, RM, 0xF, false);
  return fmaxf(x, __builtin_bit_cast(float, s));
}
__device__ __forceinline__ float wave_sum(float x) {
  x = dpp_add<0xB1, 0xF>(x);    // quad_perm xor1
  x = dpp_add<0x4E, 0xF>(x);    // quad_perm xor2
  x = dpp_add<0x141, 0xF>(x);   // row_half_mirror (xor4)
  x = dpp_add<0x140, 0xF>(x);   // row_mirror (xor8)
  x = dpp_add<0x142, 0xA>(x);   // row_bcast15 -> rows 1,3
  x = dpp_add<0x143, 0xC>(x);   // row_bcast31 -> rows 2,3
  return __builtin_bit_cast(float,
      __builtin_amdgcn_readlane(__builtin_bit_cast(int, x), 63));
}
__device__ __forceinline__ float wave_max(float x) {
  x = dpp_max<0xB1, 0xF>(x);
  x = dpp_max<0x4E, 0xF>(x);
  x = dpp_max<0x141, 0xF>(x);
  x = dpp_max<0x140, 0xF>(x);
  x = dpp_max<0x142, 0xA>(x);
  x = dpp_max<0x143, 0xC>(x);
  return __builtin_bit_cast(float,
      __builtin_amdgcn_readlane(__builtin_bit_cast(int, x), 63));
}

#define MAXIT 12
#define FEPS 8e-3f

__global__ __launch_bounds__(256) void entmax_iqi3(
    const float* __restrict__ X, const float* __restrict__ A,
    float* __restrict__ O, int nrows) {
  __shared__ float          cval[4][1024];
  __shared__ unsigned short cidx[4][1024];

  const int lane = threadIdx.x & 63;
  const int wid  = threadIdx.x >> 6;
  const long long row = (long long)blockIdx.x * 4 + wid;
  if (row >= nrows) return;

  const f4* xr4 = reinterpret_cast<const f4*>(X + row * 1024);
  f4* or4       = reinterpret_cast<f4*>(O + row * 1024);

  const int h = (int)((row >> 10) & 15);     // [B,H,Q] flattened, Q=1024
  const float a   = 1.01f + 0.98f * A[h];
  const float am1 = a - 1.0f;                // = 1/p
  const float inv = 1.0f / am1;              // = p in (1.01, 100]
  const float c1  = inv - 1.0f;

  float xs[16];
#pragma unroll
  for (int c = 0; c < 4; ++c) {
    f4 t = __builtin_nontemporal_load(xr4 + c * 64 + lane);
    xs[4*c+0] = t[0] * am1; xs[4*c+1] = t[1] * am1;
    xs[4*c+2] = t[2] * am1; xs[4*c+3] = t[3] * am1;
  }
  float m = xs[0];
#pragma unroll
  for (int j = 1; j < 16; ++j) m = fmaxf(m, xs[j]);
  m = wave_max(m);
#pragma unroll
  for (int j = 0; j < 16; ++j) xs[j] -= m;   // zs <= 0; active iff zs > -1

  // ---- count-first (nact wave-uniform) ----
  int nact = 0;
#pragma unroll
  for (int j = 0; j < 16; ++j)
    nact += (int)__popcll(__ballot(xs[j] > -1.0f));
  const int  K      = (nact + 63) >> 6;
  const bool direct = (K >= 12);             // in-place solve; inactive -> 0
  const int  KE     = direct ? 16 : K;       // eval-loop bound

  float vals[16];
  if (direct) {
#pragma unroll
    for (int k = 0; k < 16; ++k) vals[k] = xs[k];
  } else {
    int base = 0;
#pragma unroll
    for (int c = 0; c < 4; ++c) {
#pragma unroll
      for (int k = 0; k < 4; ++k) {
        const int j = 4*c + k;
        const bool act = xs[j] > -1.0f;
        const unsigned long long mk = __ballot(act);
        if (act) {
          const int pos = base + __popcll(mk & ((1ull << lane) - 1ull));
          cval[wid][pos] = xs[j];
          cidx[wid][pos] = (unsigned short)(c * 256 + lane * 4 + k);
        }
        base += __popcll(mk);
      }
    }
    for (int pos = nact + lane; pos < (K << 6); pos += 64)
      cval[wid][pos] = -2.0f;                // pad: never active
    asm volatile("s_waitcnt lgkmcnt(0)" ::: "memory");
#pragma unroll
    for (int k = 0; k < 16; ++k)
      if (k < K) vals[k] = cval[wid][lane + (k << 6)];
  }

  // ---- it0: eval at w=1 with g; exact local power-law seed ----
  float lwlo = -10.0f * am1;                 // log2(d^(-1/p)) lower bracket
  float lwhi = 0.0f;
  float w = 1.0f, lw = 0.0f;
  float p[16];
  float f, lw_p, lf_p;
  float lw_pp = 0.0f, lf_pp = 0.0f;
  bool have2 = false;
  {
    float fs = 0.0f, gs = 0.0f;
#pragma unroll
    for (int k = 0; k < 16; ++k)
      if (k < KE) {
        float u  = fmaxf(vals[k] + 1.0f, 0.0f);
        float e  = __builtin_amdgcn_exp2f(c1 * __builtin_amdgcn_logf(u));
        float pe = e * u;
        p[k] = pe; fs += pe; gs += e;
      }
    f = wave_sum(fs);
    const float g = wave_sum(gs);            // g >= 1, f >= 1 at w=1
    lw_p = 0.0f; lf_p = __builtin_amdgcn_logf(f);
    if (fabsf(f - 1.0f) > FEPS) {
      // q0 = p*g*w/f (w=1); lw1 = -lf0/q0
      float lwn = -lf_p * f * am1 / g;
      if (!(lwn > lwlo) || !(lwn < lwhi)) lwn = 0.5f * (lwlo + lwhi);
      w = __builtin_amdgcn_exp2f(lwn); lw = lwn;

      // ---- IQI / secant iterations (f only) ----
      for (int it = 1; it < MAXIT; ++it) {
        float fs2 = 0.0f;
#pragma unroll
        for (int k = 0; k < 16; ++k)
          if (k < KE) {
            float u  = fmaxf(vals[k] + w, 0.0f);
            float pe = __builtin_amdgcn_exp2f(
                inv * __builtin_amdgcn_logf(u));
            p[k] = pe; fs2 += pe;
          }
        f = wave_sum(fs2);

        float lwnew;
        if (f > 0.0f) {
          if (fabsf(f - 1.0f) <= FEPS) break;   // normalization absorbs eps
          const float lf = __builtin_amdgcn_logf(f);
          if (f > 1.0f) lwhi = lw; else lwlo = lw;

          float cand = 0.0f; bool got = false;
          if (have2) {
            // inverse quadratic interpolation to lf = 0
            const float d01 = lf - lf_p, d02 = lf - lf_pp, d12 = lf_p - lf_pp;
            const float r01 = __builtin_amdgcn_rcpf(d01);
            const float r02 = __builtin_amdgcn_rcpf(d02);
            const float r12 = __builtin_amdgcn_rcpf(d12);
            cand = lw    * lf_p * lf_pp * r01 * r02
                 - lw_p  * lf   * lf_pp * r01 * r12
                 + lw_pp * lf   * lf_p  * r02 * r12;
            got = (cand > lwlo) && (cand < lwhi);   // inf/nan fail here
          }
          if (!got) {
            const float si = (lw - lw_p) / (lf - lf_p); // secant
            cand = lw - lf * si;
            if (!(si > 0.0f) || !(cand > lwlo) || !(cand < lwhi))
              cand = 0.5f * (lwlo + lwhi);            // geometric bisect
          }
          lw_pp = lw_p; lf_pp = lf_p; lw_p = lw; lf_p = lf; have2 = true;
          lwnew = cand;
        } else {                              // underflow: w below root
          lwlo = lw;
          lwnew = 0.5f * (lwlo + lwhi);
        }
        const float wnew  = __builtin_amdgcn_exp2f(lwnew);
        if (!(fabsf(wnew - w) > 2e-5f * fmaxf(fabsf(m - w), 1.0f))) break;
        w = wnew; lw = lwnew;
      }
    }
  }

  // ---- epilogue: sum(p[]) == f from the last eval ----
  const float r = 1.0f / f;
  if (direct) {                               // identity layout
#pragma unroll
    for (int c = 0; c < 4; ++c) {
      f4 t;
      t[0] = p[4*c+0] * r; t[1] = p[4*c+1] * r;
      t[2] = p[4*c+2] * r; t[3] = p[4*c+3] * r;
      __builtin_nontemporal_store(t, or4 + c * 64 + lane);
    }
  } else {                                    // zero, scatter by cidx, store
    const f4 z = {0.0f, 0.0f, 0.0f, 0.0f};
#pragma unroll
    for (int c = 0; c < 4; ++c)
      reinterpret_cast<f4*>(&cval[wid][0])[c * 64 + lane] = z;
    asm volatile("s_waitcnt lgkmcnt(0)" ::: "memory");
#pragma unroll
    for (int k = 0; k < 16; ++k)
      if (k < K) {
        const int pos = lane + (k << 6);
        if (pos < nact) cval[wid][cidx[wid][pos]] = p[k] * r;
      }
    asm volatile("s_waitcnt lgkmcnt(0)" ::: "memory");
#pragma unroll
    for (int c = 0; c < 4; ++c) {
      f4 t = reinterpret_cast<const f4*>(&cval[wid][0])[c * 64 + lane];
      __builtin_nontemporal_store(t, or4 + c * 64 + lane);
    }
  }
}

extern "C" void kernel_launch(void* const* d_in, const int* in_sizes, int n_in,
                              void* d_out, int out_size, void* d_ws, size_t ws_size,
                              hipStream_t stream) {
  const float* X = (const float*)d_in[0];
  const float* A = (const float*)d_in[1];
  float* O       = (float*)d_out;
  const int nrows = in_sizes[0] / 1024;                 // 65536
  const int blocks = (nrows + 3) / 4;                   // 4 rows (waves) per block
  hipLaunchKernelGGL(entmax_iqi3, dim3(blocks), dim3(256), 0, stream,
                     X, A, O, nrows);
}